// Round 2
// baseline (5824.283 us; speedup 1.0000x reference)
//
#include <hip/hip_runtime.h>
#include <hip/hip_bf16.h>

#define D_MODEL 384
#define N_LAYER 4
#define VOCAB   5000
#define D_INNER 768
#define D_STATE 16
#define DT_RANK 24
#define D_CONV  4
#define BATCH   4
#define SEQ     2048
#define ROWS    (BATCH*SEQ)          // 8192

// ---------------------------------------------------------------- embed gather
__global__ __launch_bounds__(256)
void embed_gather(const int* __restrict__ tokens, const float* __restrict__ embed,
                  float* __restrict__ x)
{
    int idx = blockIdx.x * 256 + threadIdx.x;       // ROWS * 96 float4s
    int row = idx / 96, c4 = idx % 96;
    int tok = tokens[row];
    reinterpret_cast<float4*>(x)[(size_t)row * 96 + c4] =
        reinterpret_cast<const float4*>(embed)[(size_t)tok * 96 + c4];
}

// ---------------------------------------------------------------- rmsnorm
__global__ __launch_bounds__(256)
void rmsnorm_k(const float* __restrict__ xin, const float* __restrict__ w,
               float* __restrict__ xout)
{
    int row  = blockIdx.x * 4 + (threadIdx.x >> 6);
    int lane = threadIdx.x & 63;
    const float* xr = xin + (size_t)row * D_MODEL;
    float v[6]; float ss = 0.f;
    #pragma unroll
    for (int j = 0; j < 6; ++j) { v[j] = xr[lane + 64*j]; ss += v[j]*v[j]; }
    #pragma unroll
    for (int m = 32; m; m >>= 1) ss += __shfl_xor(ss, m, 64);
    float r = rsqrtf(ss * (1.f/D_MODEL) + 1e-5f);
    float* yo = xout + (size_t)row * D_MODEL;
    #pragma unroll
    for (int j = 0; j < 6; ++j) yo[lane + 64*j] = v[j] * w[lane + 64*j] * r;
}

// ---------------------------------------------------------------- conv1d + silu
__global__ __launch_bounds__(256)
void conv_silu_k(const float* __restrict__ xz, const float* __restrict__ cw,
                 const float* __restrict__ cb, float* __restrict__ xout)
{
    int idx = blockIdx.x * 256 + threadIdx.x;       // ROWS * D_INNER
    int e   = idx % D_INNER;
    int row = idx / D_INNER;
    int l   = row & (SEQ - 1);
    float acc = cb[e];
    #pragma unroll
    for (int j = 0; j < 4; ++j) {
        if (l - j >= 0)
            acc += cw[e*4 + 3 - j] * xz[(size_t)(row - j) * (2*D_INNER) + e];
    }
    xout[idx] = acc / (1.f + __expf(-acc));         // silu
}

// ---------------------------------------------------------------- generic GEMM
// C[M,N] = A[M,K] @ B[N,K]^T ; EPI: 0 = store, 1 = softplus(x+bias), 2 = C += x
template<int EPI>
__global__ __launch_bounds__(256)
void gemm_tn(const float* __restrict__ A, int lda,
             const float* __restrict__ Bw, int ldb,
             float* __restrict__ C, int ldc,
             const float* __restrict__ bias,
             int N, int K)
{
    __shared__ float As[16][132];
    __shared__ float Bs[16][132];
    int tid = threadIdx.x;
    int tx = tid & 15, ty = tid >> 4;
    int row0 = blockIdx.y * 128;
    int col0 = blockIdx.x * 128;
    float acc[8][8] = {};

    for (int k0 = 0; k0 < K; k0 += 16) {
        #pragma unroll
        for (int i = 0; i < 8; ++i) {
            int idx = tid + i * 256;
            int m = idx >> 4, k = idx & 15;
            int gk = k0 + k;
            As[k][m] = (gk < K) ? A[(size_t)(row0 + m) * lda + gk] : 0.f;
            int gn = col0 + m;
            Bs[k][m] = (gk < K && gn < N) ? Bw[(size_t)gn * ldb + gk] : 0.f;
        }
        __syncthreads();
        #pragma unroll
        for (int k = 0; k < 16; ++k) {
            float av[8], bv[8];
            #pragma unroll
            for (int i = 0; i < 4; ++i) {
                av[i]   = As[k][ty*4 + i];
                av[4+i] = As[k][64 + ty*4 + i];
                bv[i]   = Bs[k][tx*4 + i];
                bv[4+i] = Bs[k][64 + tx*4 + i];
            }
            #pragma unroll
            for (int i = 0; i < 8; ++i)
                #pragma unroll
                for (int j = 0; j < 8; ++j)
                    acc[i][j] += av[i] * bv[j];
        }
        __syncthreads();
    }

    #pragma unroll
    for (int i = 0; i < 8; ++i) {
        int m = row0 + ((i < 4) ? ty*4 + i : 64 + ty*4 + i - 4);
        #pragma unroll
        for (int j = 0; j < 8; ++j) {
            int n = col0 + ((j < 4) ? tx*4 + j : 64 + tx*4 + j - 4);
            if (n < N) {
                float v = acc[i][j];
                size_t off = (size_t)m * ldc + n;
                if (EPI == 1) {
                    v += bias[n];
                    v = fmaxf(v, 0.f) + log1pf(__expf(-fabsf(v)));  // softplus
                    C[off] = v;
                } else if (EPI == 2) {
                    C[off] += v;
                } else {
                    C[off] = v;
                }
            }
        }
    }
}

// ---------------------------------------------------------------- selective scan
// One thread per (b, e, n): 16 lanes per channel, shuffle-reduce over states.
// y is written IN PLACE over dt (same layout); safe: the stored value
// dataflow-depends on every lane's prefetched loads of row j, so all reads
// of an address complete before its overwrite; channels are wave-confined.
__global__ __launch_bounds__(256)
void scan_k(float* __restrict__ dt, const float* __restrict__ xin,
            const float* __restrict__ xz, const float* __restrict__ proj,
            const float* __restrict__ A_log, const float* __restrict__ Dp)
{
    int b = blockIdx.x / 48;
    int e = (blockIdx.x % 48) * 16 + (threadIdx.x >> 4);
    int n = threadIdx.x & 15;

    float a     = -__expf(A_log[e * D_STATE + n]);
    float dskip = Dp[e];

    size_t row0 = (size_t)b * SEQ;
    float*       pdt = dt   + row0 * D_INNER + e;      // read dt, write y
    const float* px  = xin  + row0 * D_INNER + e;
    const float* pz  = xz   + row0 * (2*D_INNER) + D_INNER + e;
    const float* pB  = proj + row0 * 56 + DT_RANK + n;

    float h = 0.f;
    for (int l0 = 0; l0 < SEQ; l0 += 16) {
        float dtv[16], xv[16], Bv[16], Cv[16];
        #pragma unroll
        for (int j = 0; j < 16; ++j) {
            dtv[j] = pdt[(size_t)j * D_INNER];
            xv[j]  = px [(size_t)j * D_INNER];
            Bv[j]  = pB [j * 56];
            Cv[j]  = pB [j * 56 + D_STATE];
        }
        float zv[16];
        if (n == 0) {
            #pragma unroll
            for (int j = 0; j < 16; ++j) zv[j] = pz[(size_t)j * (2*D_INNER)];
        }
        #pragma unroll
        for (int j = 0; j < 16; ++j) {
            float ex = __expf(dtv[j] * a);
            h = h * ex + dtv[j] * xv[j] * Bv[j];
            float yv = h * Cv[j];
            yv += __shfl_xor(yv, 1, 16);
            yv += __shfl_xor(yv, 2, 16);
            yv += __shfl_xor(yv, 4, 16);
            yv += __shfl_xor(yv, 8, 16);
            if (n == 0) {
                float g = zv[j] / (1.f + __expf(-zv[j]));   // silu(z)
                pdt[(size_t)j * D_INNER] = (yv + xv[j] * dskip) * g;
            }
        }
        pdt += 16 * D_INNER; px += 16 * D_INNER;
        pz  += 16 * (2*D_INNER); pB += 16 * 56;
    }
}

// ---------------------------------------------------------------- launch
extern "C" void kernel_launch(void* const* d_in, const int* in_sizes, int n_in,
                              void* d_out, int out_size, void* d_ws, size_t ws_size,
                              hipStream_t stream)
{
    const int*   tokens       = (const int*)  d_in[0];
    const float* embed        = (const float*)d_in[1];
    const float* norm_w       = (const float*)d_in[2];
    const float* in_proj_w    = (const float*)d_in[3];
    const float* conv_w       = (const float*)d_in[4];
    const float* conv_b       = (const float*)d_in[5];
    const float* x_proj_w     = (const float*)d_in[6];
    const float* dt_proj_w    = (const float*)d_in[7];
    const float* dt_proj_b    = (const float*)d_in[8];
    const float* A_log        = (const float*)d_in[9];
    const float* D_param      = (const float*)d_in[10];
    const float* out_proj_w   = (const float*)d_in[11];
    const float* final_norm_w = (const float*)d_in[12];
    float* out = (float*)d_out;

    // Workspace layout (77.3 MB): x, xn, xin, proj, dt(=y)
    float* ws   = (float*)d_ws;
    float* x    = ws;                            // 8192*384
    float* xn   = x    + (size_t)ROWS*D_MODEL;   // 8192*384
    float* xin  = xn   + (size_t)ROWS*D_MODEL;   // 8192*768
    float* proj = xin  + (size_t)ROWS*D_INNER;   // 8192*56
    float* dt   = proj + (size_t)ROWS*56;        // 8192*768 (scan overwrites with y)
    // xz lives in d_out (12.58M floats of 40.96M); dead before final lm_head.
    float* xz   = out;

    dim3 blk(256);
    // embed
    embed_gather<<<ROWS*96/256, blk, 0, stream>>>(tokens, embed, x);

    for (int i = 0; i < N_LAYER; ++i) {
        rmsnorm_k<<<ROWS/4, blk, 0, stream>>>(x, norm_w + i*D_MODEL, xn);
        // in_proj: 8192 x 1536 x 384
        gemm_tn<0><<<dim3(1536/128, ROWS/128), blk, 0, stream>>>(
            xn, D_MODEL, in_proj_w + (size_t)i*2*D_INNER*D_MODEL, D_MODEL,
            xz, 2*D_INNER, nullptr, 2*D_INNER, D_MODEL);
        // conv + silu
        conv_silu_k<<<ROWS*D_INNER/256, blk, 0, stream>>>(
            xz, conv_w + i*D_INNER*D_CONV, conv_b + i*D_INNER, xin);
        // x_proj: 8192 x 56 x 768
        gemm_tn<0><<<dim3(1, ROWS/128), blk, 0, stream>>>(
            xin, D_INNER, x_proj_w + (size_t)i*56*D_INNER, D_INNER,
            proj, 56, nullptr, 56, D_INNER);
        // dt_proj + softplus: 8192 x 768 x 24
        gemm_tn<1><<<dim3(D_INNER/128, ROWS/128), blk, 0, stream>>>(
            proj, 56, dt_proj_w + (size_t)i*D_INNER*DT_RANK, DT_RANK,
            dt, D_INNER, dt_proj_b + i*D_INNER, D_INNER, DT_RANK);
        // selective scan + D-skip + gate (y overwrites dt in place)
        scan_k<<<BATCH*48, blk, 0, stream>>>(
            dt, xin, xz, proj, A_log + (size_t)i*D_INNER*D_STATE,
            D_param + i*D_INNER);
        // out_proj + residual: 8192 x 384 x 768, x += ...
        gemm_tn<2><<<dim3(D_MODEL/128, ROWS/128), blk, 0, stream>>>(
            dt, D_INNER, out_proj_w + (size_t)i*D_MODEL*D_INNER, D_INNER,
            x, D_MODEL, nullptr, D_MODEL, D_INNER);
    }

    rmsnorm_k<<<ROWS/4, blk, 0, stream>>>(x, final_norm_w, xn);
    // lm_head: 8192 x 5000 x 384 (overwrites xz region of d_out)
    gemm_tn<0><<<dim3((VOCAB+127)/128, ROWS/128), blk, 0, stream>>>(
        xn, D_MODEL, embed, D_MODEL, out, VOCAB, nullptr, VOCAB, D_MODEL);
}

// Round 3
// 3717.625 us; speedup vs baseline: 1.5667x; 1.5667x over previous
//
#include <hip/hip_runtime.h>
#include <hip/hip_bf16.h>

#define D_MODEL 384
#define N_LAYER 4
#define VOCAB   5000
#define D_INNER 768
#define D_STATE 16
#define DT_RANK 24
#define D_CONV  4
#define BATCH   4
#define SEQ     2048
#define ROWS    (BATCH*SEQ)          // 8192

typedef __attribute__((ext_vector_type(8))) short bf16x8;
typedef __attribute__((ext_vector_type(4))) float f32x4;

// fp32 -> bf16 (RNE), finite inputs only
static __device__ __forceinline__ ushort f2b(float f) {
    uint u = __float_as_uint(f);
    return (ushort)((u + 0x7FFFu + ((u >> 16) & 1u)) >> 16);
}

// ---------------------------------------------------------------- fp32->bf16 bulk
__global__ __launch_bounds__(256)
void f2b_k(const float* __restrict__ in, ushort* __restrict__ out, int n4)
{
    int i = blockIdx.x * 256 + threadIdx.x;
    if (i < n4) {
        float4 v = reinterpret_cast<const float4*>(in)[i];
        ushort4 o;
        o.x = f2b(v.x); o.y = f2b(v.y); o.z = f2b(v.z); o.w = f2b(v.w);
        reinterpret_cast<ushort4*>(out)[i] = o;
    }
}

// ---------------------------------------------------------------- embed gather
__global__ __launch_bounds__(256)
void embed_gather(const int* __restrict__ tokens, const float* __restrict__ embed,
                  float* __restrict__ x)
{
    int idx = blockIdx.x * 256 + threadIdx.x;       // ROWS * 96 float4s
    int row = idx / 96, c4 = idx % 96;
    int tok = tokens[row];
    reinterpret_cast<float4*>(x)[(size_t)row * 96 + c4] =
        reinterpret_cast<const float4*>(embed)[(size_t)tok * 96 + c4];
}

// ---------------------------------------------------------------- rmsnorm -> bf16
__global__ __launch_bounds__(256)
void rmsnorm_k(const float* __restrict__ xin, const float* __restrict__ w,
               ushort* __restrict__ xout)
{
    int row  = blockIdx.x * 4 + (threadIdx.x >> 6);
    int lane = threadIdx.x & 63;
    const float* xr = xin + (size_t)row * D_MODEL;
    float v[6]; float ss = 0.f;
    #pragma unroll
    for (int j = 0; j < 6; ++j) { v[j] = xr[lane + 64*j]; ss += v[j]*v[j]; }
    #pragma unroll
    for (int m = 32; m; m >>= 1) ss += __shfl_xor(ss, m, 64);
    float r = rsqrtf(ss * (1.f/D_MODEL) + 1e-5f);
    ushort* yo = xout + (size_t)row * D_MODEL;
    #pragma unroll
    for (int j = 0; j < 6; ++j) yo[lane + 64*j] = f2b(v[j] * w[lane + 64*j] * r);
}

// ---------------------------------------------------------------- conv1d + silu
__global__ __launch_bounds__(256)
void conv_silu_k(const float* __restrict__ xz, const float* __restrict__ cw,
                 const float* __restrict__ cb, float* __restrict__ xout)
{
    int idx = blockIdx.x * 256 + threadIdx.x;       // ROWS * D_INNER
    int e   = idx % D_INNER;
    int row = idx / D_INNER;
    int l   = row & (SEQ - 1);
    float acc = cb[e];
    #pragma unroll
    for (int j = 0; j < 4; ++j) {
        if (l - j >= 0)
            acc += cw[e*4 + 3 - j] * xz[(size_t)(row - j) * (2*D_INNER) + e];
    }
    xout[idx] = acc / (1.f + __expf(-acc));         // silu
}

// ---------------------------------------------------------------- bf16 MFMA GEMM
// C[M,N](f32) = A[M,K](bf16) @ B[N,K](bf16)^T.  EPI: 0 = store, 2 = C += v.
// Direct global->register fragments (A,B rows are contiguous 16B k-slices).
// Requires K % 32 == 0, M % 128 == 0; B rows readable up to col rounded to 128.
template<int EPI>
__global__ __launch_bounds__(256)
void gemm_mfma(const ushort* __restrict__ A, int lda,
               const ushort* __restrict__ B, int ldb,
               float* __restrict__ C, int ldc,
               int N, int K)
{
    int wave = threadIdx.x >> 6;
    int lane = threadIdx.x & 63;
    int wr = wave >> 1, wc = wave & 1;              // 2x2 waves -> 128x128 block
    int row0 = blockIdx.y * 128 + wr * 64;
    int col0 = blockIdx.x * 128 + wc * 64;
    int l15 = lane & 15, g = lane >> 4;             // g selects k-group of 8

    f32x4 acc[4][4] = {};
    for (int k0 = 0; k0 < K; k0 += 32) {
        bf16x8 af[4], bf_[4];
        int ka = k0 + g * 8;
        #pragma unroll
        for (int i = 0; i < 4; ++i)
            af[i] = *reinterpret_cast<const bf16x8*>(&A[(size_t)(row0 + i*16 + l15) * lda + ka]);
        #pragma unroll
        for (int j = 0; j < 4; ++j)
            bf_[j] = *reinterpret_cast<const bf16x8*>(&B[(size_t)(col0 + j*16 + l15) * ldb + ka]);
        #pragma unroll
        for (int i = 0; i < 4; ++i)
            #pragma unroll
            for (int j = 0; j < 4; ++j)
                acc[i][j] = __builtin_amdgcn_mfma_f32_16x16x32_bf16(af[i], bf_[j], acc[i][j], 0, 0, 0);
    }

    // C/D layout: col = lane&15, row = (lane>>4)*4 + reg   [m89-verified]
    #pragma unroll
    for (int i = 0; i < 4; ++i) {
        int r = row0 + i*16 + g*4;
        #pragma unroll
        for (int j = 0; j < 4; ++j) {
            int c = col0 + j*16 + l15;
            if (c < N) {
                #pragma unroll
                for (int rr = 0; rr < 4; ++rr) {
                    size_t off = (size_t)(r + rr) * ldc + c;
                    if (EPI == 2) C[off] += acc[i][j][rr];
                    else          C[off]  = acc[i][j][rr];
                }
            }
        }
    }
}

// ---------------------------------------------------------------- fp32 GEMM (small)
// C[M,N] = A[M,K] @ B[N,K]^T ; EPI: 0 = store, 1 = softplus(x+bias)
template<int EPI>
__global__ __launch_bounds__(256)
void gemm_tn(const float* __restrict__ A, int lda,
             const float* __restrict__ Bw, int ldb,
             float* __restrict__ C, int ldc,
             const float* __restrict__ bias,
             int N, int K)
{
    __shared__ float As[16][132];
    __shared__ float Bs[16][132];
    int tid = threadIdx.x;
    int tx = tid & 15, ty = tid >> 4;
    int row0 = blockIdx.y * 128;
    int col0 = blockIdx.x * 128;
    float acc[8][8] = {};

    for (int k0 = 0; k0 < K; k0 += 16) {
        #pragma unroll
        for (int i = 0; i < 8; ++i) {
            int idx = tid + i * 256;
            int m = idx >> 4, k = idx & 15;
            int gk = k0 + k;
            As[k][m] = (gk < K) ? A[(size_t)(row0 + m) * lda + gk] : 0.f;
            int gn = col0 + m;
            Bs[k][m] = (gk < K && gn < N) ? Bw[(size_t)gn * ldb + gk] : 0.f;
        }
        __syncthreads();
        #pragma unroll
        for (int k = 0; k < 16; ++k) {
            float av[8], bv[8];
            #pragma unroll
            for (int i = 0; i < 4; ++i) {
                av[i]   = As[k][ty*4 + i];
                av[4+i] = As[k][64 + ty*4 + i];
                bv[i]   = Bs[k][tx*4 + i];
                bv[4+i] = Bs[k][64 + tx*4 + i];
            }
            #pragma unroll
            for (int i = 0; i < 8; ++i)
                #pragma unroll
                for (int j = 0; j < 8; ++j)
                    acc[i][j] += av[i] * bv[j];
        }
        __syncthreads();
    }

    #pragma unroll
    for (int i = 0; i < 8; ++i) {
        int m = row0 + ((i < 4) ? ty*4 + i : 64 + ty*4 + i - 4);
        #pragma unroll
        for (int j = 0; j < 8; ++j) {
            int n = col0 + ((j < 4) ? tx*4 + j : 64 + tx*4 + j - 4);
            if (n < N) {
                float v = acc[i][j];
                size_t off = (size_t)m * ldc + n;
                if (EPI == 1) {
                    v += bias[n];
                    v = fmaxf(v, 0.f) + log1pf(__expf(-fabsf(v)));  // softplus
                    C[off] = v;
                } else {
                    C[off] = v;
                }
            }
        }
    }
}

// ---------------------------------------------------------------- selective scan
// One thread per (b, e, n): 16 lanes per channel, shuffle-reduce over states.
// Writes y as bf16 (feeds out_proj MFMA).
__global__ __launch_bounds__(256)
void scan_k(const float* __restrict__ dt, const float* __restrict__ xin,
            const float* __restrict__ xz, const float* __restrict__ proj,
            const float* __restrict__ A_log, const float* __restrict__ Dp,
            ushort* __restrict__ y)
{
    int b = blockIdx.x / 48;
    int e = (blockIdx.x % 48) * 16 + (threadIdx.x >> 4);
    int n = threadIdx.x & 15;

    float a     = -__expf(A_log[e * D_STATE + n]);
    float dskip = Dp[e];

    size_t row0 = (size_t)b * SEQ;
    const float* pdt = dt   + row0 * D_INNER + e;
    const float* px  = xin  + row0 * D_INNER + e;
    const float* pz  = xz   + row0 * (2*D_INNER) + D_INNER + e;
    const float* pB  = proj + row0 * 56 + DT_RANK + n;
    ushort*      py  = y    + row0 * D_INNER + e;

    float h = 0.f;
    for (int l0 = 0; l0 < SEQ; l0 += 16) {
        float dtv[16], xv[16], Bv[16], Cv[16];
        #pragma unroll
        for (int j = 0; j < 16; ++j) {
            dtv[j] = pdt[(size_t)j * D_INNER];
            xv[j]  = px [(size_t)j * D_INNER];
            Bv[j]  = pB [j * 56];
            Cv[j]  = pB [j * 56 + D_STATE];
        }
        float zv[16];
        if (n == 0) {
            #pragma unroll
            for (int j = 0; j < 16; ++j) zv[j] = pz[(size_t)j * (2*D_INNER)];
        }
        #pragma unroll
        for (int j = 0; j < 16; ++j) {
            float ex = __expf(dtv[j] * a);
            h = h * ex + dtv[j] * xv[j] * Bv[j];
            float yv = h * Cv[j];
            yv += __shfl_xor(yv, 1, 16);
            yv += __shfl_xor(yv, 2, 16);
            yv += __shfl_xor(yv, 4, 16);
            yv += __shfl_xor(yv, 8, 16);
            if (n == 0) {
                float g = zv[j] / (1.f + __expf(-zv[j]));   // silu(z)
                py[(size_t)j * D_INNER] = f2b((yv + xv[j] * dskip) * g);
            }
        }
        pdt += 16 * D_INNER; px += 16 * D_INNER;
        pz  += 16 * (2*D_INNER); pB += 16 * 56; py += 16 * D_INNER;
    }
}

// ---------------------------------------------------------------- launch
extern "C" void kernel_launch(void* const* d_in, const int* in_sizes, int n_in,
                              void* d_out, int out_size, void* d_ws, size_t ws_size,
                              hipStream_t stream)
{
    const int*   tokens       = (const int*)  d_in[0];
    const float* embed        = (const float*)d_in[1];
    const float* norm_w       = (const float*)d_in[2];
    const float* in_proj_w    = (const float*)d_in[3];
    const float* conv_w       = (const float*)d_in[4];
    const float* conv_b       = (const float*)d_in[5];
    const float* x_proj_w     = (const float*)d_in[6];
    const float* dt_proj_w    = (const float*)d_in[7];
    const float* dt_proj_b    = (const float*)d_in[8];
    const float* A_log        = (const float*)d_in[9];
    const float* D_param      = (const float*)d_in[10];
    const float* out_proj_w   = (const float*)d_in[11];
    const float* final_norm_w = (const float*)d_in[12];
    float* out = (float*)d_out;

    // ---- workspace (floats): x, proj, then bf16 buffers (ushort overlays)
    float* ws   = (float*)d_ws;
    float*  x     = ws;                                   // 3,145,728 f
    float*  proj  = x + (size_t)ROWS*D_MODEL;             // 458,752 f
    ushort* xn_b  = (ushort*)(ws + 3604480);              // 3,145,728 us
    ushort* inw_b = (ushort*)(ws + 5177344);              // 2,359,296 us
    ushort* outw_b= (ushort*)(ws + 6356992);              // 1,179,648 us
    ushort* emb_b = (ushort*)(ws + 6946816);              // 5120*384 us (rows>=5000 uninit, never stored)

    // ---- big fp32 scratch lives in d_out (dead before final lm_head)
    float*  xz   = out;                                   // 12,582,912 f
    float*  xin  = out + 12582912;                        // 6,291,456 f
    float*  dt   = out + 18874368;                        // 6,291,456 f
    ushort* y_b  = (ushort*)(out + 25165824);             // 6,291,456 us

    dim3 blk(256);

    // one-shot weight conversions (fp32 -> bf16)
    f2b_k<<<(N_LAYER*2*D_INNER*D_MODEL/4 + 255)/256, blk, 0, stream>>>(in_proj_w,  inw_b,  N_LAYER*2*D_INNER*D_MODEL/4);
    f2b_k<<<(N_LAYER*D_MODEL*D_INNER/4  + 255)/256, blk, 0, stream>>>(out_proj_w, outw_b, N_LAYER*D_MODEL*D_INNER/4);
    f2b_k<<<(VOCAB*D_MODEL/4            + 255)/256, blk, 0, stream>>>(embed,      emb_b,  VOCAB*D_MODEL/4);

    embed_gather<<<ROWS*96/256, blk, 0, stream>>>(tokens, embed, x);

    for (int i = 0; i < N_LAYER; ++i) {
        rmsnorm_k<<<ROWS/4, blk, 0, stream>>>(x, norm_w + i*D_MODEL, xn_b);
        // in_proj: 8192 x 1536 x 384  (bf16 MFMA)
        gemm_mfma<0><<<dim3(1536/128, ROWS/128), blk, 0, stream>>>(
            xn_b, D_MODEL, inw_b + (size_t)i*2*D_INNER*D_MODEL, D_MODEL,
            xz, 2*D_INNER, 2*D_INNER, D_MODEL);
        // conv + silu
        conv_silu_k<<<ROWS*D_INNER/256, blk, 0, stream>>>(
            xz, conv_w + i*D_INNER*D_CONV, conv_b + i*D_INNER, xin);
        // x_proj: 8192 x 56 x 768 (fp32)
        gemm_tn<0><<<dim3(1, ROWS/128), blk, 0, stream>>>(
            xin, D_INNER, x_proj_w + (size_t)i*56*D_INNER, D_INNER,
            proj, 56, nullptr, 56, D_INNER);
        // dt_proj + softplus: 8192 x 768 x 24 (fp32)
        gemm_tn<1><<<dim3(D_INNER/128, ROWS/128), blk, 0, stream>>>(
            proj, 56, dt_proj_w + (size_t)i*D_INNER*DT_RANK, DT_RANK,
            dt, D_INNER, dt_proj_b + i*D_INNER, D_INNER, DT_RANK);
        // selective scan + D-skip + gate -> y_b (bf16)
        scan_k<<<BATCH*48, blk, 0, stream>>>(
            dt, xin, xz, proj, A_log + (size_t)i*D_INNER*D_STATE,
            D_param + i*D_INNER, y_b);
        // out_proj + residual: 8192 x 384 x 768 (bf16 MFMA, C += v)
        gemm_mfma<2><<<dim3(D_MODEL/128, ROWS/128), blk, 0, stream>>>(
            y_b, D_INNER, outw_b + (size_t)i*D_MODEL*D_INNER, D_INNER,
            x, D_MODEL, D_MODEL, D_INNER);
    }

    rmsnorm_k<<<ROWS/4, blk, 0, stream>>>(x, final_norm_w, xn_b);
    // lm_head: 8192 x 5000 x 384 (bf16 MFMA; emb_b padded to 5120 rows)
    gemm_mfma<0><<<dim3((VOCAB+127)/128, ROWS/128), blk, 0, stream>>>(
        xn_b, D_MODEL, emb_b, D_MODEL, out, VOCAB, VOCAB, D_MODEL);
}

// Round 4
// 1582.041 us; speedup vs baseline: 3.6815x; 2.3499x over previous
//
#include <hip/hip_runtime.h>
#include <hip/hip_bf16.h>

#define D_MODEL 384
#define N_LAYER 4
#define VOCAB   5000
#define D_INNER 768
#define D_STATE 16
#define DT_RANK 24
#define D_CONV  4
#define BATCH   4
#define SEQ     2048
#define ROWS    (BATCH*SEQ)          // 8192
#define NCHUNK  32
#define CLEN    64                   // NCHUNK*CLEN == SEQ

typedef __attribute__((ext_vector_type(8))) short bf16x8;
typedef __attribute__((ext_vector_type(4))) float f32x4;

// fp32 -> bf16 (RNE), finite inputs only
static __device__ __forceinline__ ushort f2b(float f) {
    uint u = __float_as_uint(f);
    return (ushort)((u + 0x7FFFu + ((u >> 16) & 1u)) >> 16);
}

// ---------------------------------------------------------------- fp32->bf16 bulk
__global__ __launch_bounds__(256)
void f2b_k(const float* __restrict__ in, ushort* __restrict__ out, int n4)
{
    int i = blockIdx.x * 256 + threadIdx.x;
    if (i < n4) {
        float4 v = reinterpret_cast<const float4*>(in)[i];
        ushort4 o;
        o.x = f2b(v.x); o.y = f2b(v.y); o.z = f2b(v.z); o.w = f2b(v.w);
        reinterpret_cast<ushort4*>(out)[i] = o;
    }
}

// pad x_proj_w [4][56][768] -> bf16 [4][128][768] (rows 56..127 zero)
__global__ __launch_bounds__(256)
void pad_xpw(const float* __restrict__ w, ushort* __restrict__ o)
{
    int i = blockIdx.x * 256 + threadIdx.x;          // 4*128*768
    int l = i / (128*768); int rk = i % (128*768);
    int r = rk / 768, k = rk % 768;
    float v = (r < 56) ? w[((size_t)l*56 + r)*768 + k] : 0.f;
    o[i] = f2b(v);
}

// pad dt_proj_w [4][768][24] -> bf16 [4][768][32] (k 24..31 zero)
__global__ __launch_bounds__(256)
void pad_dtw(const float* __restrict__ w, ushort* __restrict__ o)
{
    int i = blockIdx.x * 256 + threadIdx.x;          // 4*768*32
    int l = i / (768*32); int ek = i % (768*32);
    int e = ek / 32, k = ek % 32;
    float v = (k < 24) ? w[((size_t)l*768 + e)*24 + k] : 0.f;
    o[i] = f2b(v);
}

// ---------------------------------------------------------------- embed gather
__global__ __launch_bounds__(256)
void embed_gather(const int* __restrict__ tokens, const float* __restrict__ embed,
                  float* __restrict__ x)
{
    int idx = blockIdx.x * 256 + threadIdx.x;       // ROWS * 96 float4s
    int row = idx / 96, c4 = idx % 96;
    int tok = tokens[row];
    reinterpret_cast<float4*>(x)[(size_t)row * 96 + c4] =
        reinterpret_cast<const float4*>(embed)[(size_t)tok * 96 + c4];
}

// ---------------------------------------------------------------- rmsnorm -> bf16
__global__ __launch_bounds__(256)
void rmsnorm_k(const float* __restrict__ xin, const float* __restrict__ w,
               ushort* __restrict__ xout)
{
    int row  = blockIdx.x * 4 + (threadIdx.x >> 6);
    int lane = threadIdx.x & 63;
    const float* xr = xin + (size_t)row * D_MODEL;
    float v[6]; float ss = 0.f;
    #pragma unroll
    for (int j = 0; j < 6; ++j) { v[j] = xr[lane + 64*j]; ss += v[j]*v[j]; }
    #pragma unroll
    for (int m = 32; m; m >>= 1) ss += __shfl_xor(ss, m, 64);
    float r = rsqrtf(ss * (1.f/D_MODEL) + 1e-5f);
    ushort* yo = xout + (size_t)row * D_MODEL;
    #pragma unroll
    for (int j = 0; j < 6; ++j) yo[lane + 64*j] = f2b(v[j] * w[lane + 64*j] * r);
}

// ---------------------------------------------------------------- conv1d + silu
__global__ __launch_bounds__(256)
void conv_silu_k(const float* __restrict__ xz, const float* __restrict__ cw,
                 const float* __restrict__ cb, float* __restrict__ xout,
                 ushort* __restrict__ xout_b)
{
    int idx = blockIdx.x * 256 + threadIdx.x;       // ROWS * D_INNER
    int e   = idx % D_INNER;
    int row = idx / D_INNER;
    int l   = row & (SEQ - 1);
    float acc = cb[e];
    #pragma unroll
    for (int j = 0; j < 4; ++j) {
        if (l - j >= 0)
            acc += cw[e*4 + 3 - j] * xz[(size_t)(row - j) * (2*D_INNER) + e];
    }
    float s = acc / (1.f + __expf(-acc));           // silu
    xout[idx]   = s;
    xout_b[idx] = f2b(s);
}

// ---------------------------------------------------------------- bf16 MFMA GEMM
// C[M,N](f32) = A[M,K](bf16) @ B[N,K](bf16)^T.
// EPI: 0 store | 1 softplus(v+bias[col]) | 2 C+= | 3 store f32 + bf16 copy.
// Requires K%32==0, M%128==0; B rows readable up to col rounded up to 128.
template<int EPI>
__global__ __launch_bounds__(256)
void gemm_mfma(const ushort* __restrict__ A, int lda,
               const ushort* __restrict__ B, int ldb,
               float* __restrict__ C, int ldc,
               ushort* __restrict__ Cb, const float* __restrict__ bias,
               int N, int K)
{
    int wave = threadIdx.x >> 6;
    int lane = threadIdx.x & 63;
    int wr = wave >> 1, wc = wave & 1;              // 2x2 waves -> 128x128 block
    int row0 = blockIdx.y * 128 + wr * 64;
    int col0 = blockIdx.x * 128 + wc * 64;
    int l15 = lane & 15, g = lane >> 4;             // g selects k-group of 8

    f32x4 acc[4][4] = {};
    for (int k0 = 0; k0 < K; k0 += 32) {
        bf16x8 af[4], bf_[4];
        int ka = k0 + g * 8;
        #pragma unroll
        for (int i = 0; i < 4; ++i)
            af[i] = *reinterpret_cast<const bf16x8*>(&A[(size_t)(row0 + i*16 + l15) * lda + ka]);
        #pragma unroll
        for (int j = 0; j < 4; ++j)
            bf_[j] = *reinterpret_cast<const bf16x8*>(&B[(size_t)(col0 + j*16 + l15) * ldb + ka]);
        #pragma unroll
        for (int i = 0; i < 4; ++i)
            #pragma unroll
            for (int j = 0; j < 4; ++j)
                acc[i][j] = __builtin_amdgcn_mfma_f32_16x16x32_bf16(af[i], bf_[j], acc[i][j], 0, 0, 0);
    }

    // C/D layout: col = lane&15, row = (lane>>4)*4 + reg
    #pragma unroll
    for (int i = 0; i < 4; ++i) {
        int r = row0 + i*16 + g*4;
        #pragma unroll
        for (int j = 0; j < 4; ++j) {
            int c = col0 + j*16 + l15;
            if (c < N) {
                #pragma unroll
                for (int rr = 0; rr < 4; ++rr) {
                    float v = acc[i][j][rr];
                    size_t off = (size_t)(r + rr) * ldc + c;
                    if (EPI == 1) {
                        v += bias[c];
                        v = fmaxf(v, 0.f) + log1pf(__expf(-fabsf(v)));   // softplus
                        C[off] = v;
                    } else if (EPI == 2) {
                        C[off] += v;
                    } else {
                        C[off] = v;
                        if (EPI == 3) Cb[off] = f2b(v);
                    }
                }
            }
        }
    }
}

// ---------------------------------------------------------------- chunked scan
// Pass 1: per-chunk local scan from h=0 -> h_end, decay = exp(a*sum(dt))
__global__ __launch_bounds__(256)
void scan_p1(const float* __restrict__ dt, const float* __restrict__ xin,
             const float* __restrict__ proj, const float* __restrict__ A_log,
             float* __restrict__ h_end, float* __restrict__ decay)
{
    int b = blockIdx.z, c = blockIdx.y;
    int e = blockIdx.x * 16 + (threadIdx.x >> 4);
    int n = threadIdx.x & 15;
    float a = -__expf(A_log[e * D_STATE + n]);

    size_t r0 = (size_t)b * SEQ + (size_t)c * CLEN;
    const float* pdt = dt   + r0 * D_INNER + e;
    const float* px  = xin  + r0 * D_INNER + e;
    const float* pB  = proj + r0 * 56 + DT_RANK + n;

    float h = 0.f, S = 0.f;
    for (int l0 = 0; l0 < CLEN; l0 += 16) {
        float dtv[16], xv[16], Bv[16];
        #pragma unroll
        for (int j = 0; j < 16; ++j) {
            dtv[j] = pdt[(size_t)j * D_INNER];
            xv[j]  = px [(size_t)j * D_INNER];
            Bv[j]  = pB [j * 56];
        }
        #pragma unroll
        for (int j = 0; j < 16; ++j) {
            float ex = __expf(dtv[j] * a);
            h = h * ex + dtv[j] * xv[j] * Bv[j];
            S += dtv[j];
        }
        pdt += 16 * D_INNER; px += 16 * D_INNER; pB += 16 * 56;
    }
    size_t idx = (((size_t)b * NCHUNK + c) * D_INNER + e) * D_STATE + n;
    h_end[idx] = h;
    decay[idx] = __expf(a * S);
}

// Pass 2: sequential chunk combine -> h_init (state entering each chunk)
__global__ __launch_bounds__(256)
void scan_p2(const float* __restrict__ h_end, const float* __restrict__ decay,
             float* __restrict__ h_init)
{
    int t = blockIdx.x * 256 + threadIdx.x;          // (b, e, n): 49152 threads
    int b  = t / (D_INNER * D_STATE);
    int en = t % (D_INNER * D_STATE);
    size_t base = (size_t)b * NCHUNK * D_INNER * D_STATE + en;
    float h = 0.f;
    for (int c = 0; c < NCHUNK; ++c) {
        size_t idx = base + (size_t)c * D_INNER * D_STATE;
        h_init[idx] = h;
        h = h_end[idx] + decay[idx] * h;
    }
}

// Pass 3: re-scan each chunk from h_init; y + D-skip + gate -> bf16
__global__ __launch_bounds__(256)
void scan_p3(const float* __restrict__ dt, const float* __restrict__ xin,
             const float* __restrict__ xz, const float* __restrict__ proj,
             const float* __restrict__ A_log, const float* __restrict__ Dp,
             const float* __restrict__ h_init, ushort* __restrict__ y)
{
    int b = blockIdx.z, c = blockIdx.y;
    int e = blockIdx.x * 16 + (threadIdx.x >> 4);
    int n = threadIdx.x & 15;
    float a     = -__expf(A_log[e * D_STATE + n]);
    float dskip = Dp[e];

    size_t r0 = (size_t)b * SEQ + (size_t)c * CLEN;
    const float* pdt = dt   + r0 * D_INNER + e;
    const float* px  = xin  + r0 * D_INNER + e;
    const float* pz  = xz   + r0 * (2*D_INNER) + D_INNER + e;
    const float* pB  = proj + r0 * 56 + DT_RANK + n;
    ushort*      py  = y    + r0 * D_INNER + e;

    float h = h_init[(((size_t)b * NCHUNK + c) * D_INNER + e) * D_STATE + n];

    for (int l0 = 0; l0 < CLEN; l0 += 16) {
        float dtv[16], xv[16], Bv[16], Cv[16];
        #pragma unroll
        for (int j = 0; j < 16; ++j) {
            dtv[j] = pdt[(size_t)j * D_INNER];
            xv[j]  = px [(size_t)j * D_INNER];
            Bv[j]  = pB [j * 56];
            Cv[j]  = pB [j * 56 + D_STATE];
        }
        float zv[16];
        if (n == 0) {
            #pragma unroll
            for (int j = 0; j < 16; ++j) zv[j] = pz[(size_t)j * (2*D_INNER)];
        }
        #pragma unroll
        for (int j = 0; j < 16; ++j) {
            float ex = __expf(dtv[j] * a);
            h = h * ex + dtv[j] * xv[j] * Bv[j];
            float yv = h * Cv[j];
            yv += __shfl_xor(yv, 1, 16);
            yv += __shfl_xor(yv, 2, 16);
            yv += __shfl_xor(yv, 4, 16);
            yv += __shfl_xor(yv, 8, 16);
            if (n == 0) {
                float g = zv[j] / (1.f + __expf(-zv[j]));   // silu(z)
                py[(size_t)j * D_INNER] = f2b((yv + xv[j] * dskip) * g);
            }
        }
        pdt += 16 * D_INNER; px += 16 * D_INNER;
        pz  += 16 * (2*D_INNER); pB += 16 * 56; py += 16 * D_INNER;
    }
}

// ---------------------------------------------------------------- launch
extern "C" void kernel_launch(void* const* d_in, const int* in_sizes, int n_in,
                              void* d_out, int out_size, void* d_ws, size_t ws_size,
                              hipStream_t stream)
{
    const int*   tokens       = (const int*)  d_in[0];
    const float* embed        = (const float*)d_in[1];
    const float* norm_w       = (const float*)d_in[2];
    const float* in_proj_w    = (const float*)d_in[3];
    const float* conv_w       = (const float*)d_in[4];
    const float* conv_b       = (const float*)d_in[5];
    const float* x_proj_w     = (const float*)d_in[6];
    const float* dt_proj_w    = (const float*)d_in[7];
    const float* dt_proj_b    = (const float*)d_in[8];
    const float* A_log        = (const float*)d_in[9];
    const float* D_param      = (const float*)d_in[10];
    const float* out_proj_w   = (const float*)d_in[11];
    const float* final_norm_w = (const float*)d_in[12];
    float* out = (float*)d_out;

    // ---- workspace map (float offsets)
    float* ws = (float*)d_ws;
    float*  x      = ws;                          // 3,145,728
    float*  proj   = ws + 3145728;                // 458,752
    ushort* xn_b   = (ushort*)(ws + 3604480);     // 3,145,728 us
    ushort* inw_b  = (ushort*)(ws + 5177344);     // 2,359,296 us
    ushort* outw_b = (ushort*)(ws + 6356992);     // 1,179,648 us
    ushort* emb_b  = (ushort*)(ws + 6946816);     // 5120*384 us (rows>=5000: poison, never stored)
    ushort* xpw_b  = (ushort*)(ws + 7929856);     // 4*128*768 us
    ushort* dtw_b  = (ushort*)(ws + 8126464);     // 4*768*32 us
    ushort* proj_b = (ushort*)(ws + 8175616);     // 8192*56 us
    float*  h_end  = ws + 8404992;                // 1,572,864
    float*  decay  = ws + 9977856;                // 1,572,864
    float*  h_init = ws + 11550720;               // 1,572,864

    // ---- big scratch in d_out (dead before final lm_head)
    float*  xz    = out;                          // 12,582,912 f
    float*  xin   = out + 12582912;               // 6,291,456 f
    float*  dtf   = out + 18874368;               // 6,291,456 f
    ushort* y_b   = (ushort*)(out + 25165824);    // 6,291,456 us
    ushort* xin_b = (ushort*)(out + 28311552);    // 6,291,456 us

    dim3 blk(256);

    // one-shot weight conversions
    f2b_k<<<(N_LAYER*2*D_INNER*D_MODEL/4 + 255)/256, blk, 0, stream>>>(in_proj_w,  inw_b,  N_LAYER*2*D_INNER*D_MODEL/4);
    f2b_k<<<(N_LAYER*D_MODEL*D_INNER/4  + 255)/256, blk, 0, stream>>>(out_proj_w, outw_b, N_LAYER*D_MODEL*D_INNER/4);
    f2b_k<<<(VOCAB*D_MODEL/4            + 255)/256, blk, 0, stream>>>(embed,      emb_b,  VOCAB*D_MODEL/4);
    pad_xpw<<<N_LAYER*128*768/256, blk, 0, stream>>>(x_proj_w, xpw_b);
    pad_dtw<<<N_LAYER*768*32/256,  blk, 0, stream>>>(dt_proj_w, dtw_b);

    embed_gather<<<ROWS*96/256, blk, 0, stream>>>(tokens, embed, x);

    for (int i = 0; i < N_LAYER; ++i) {
        rmsnorm_k<<<ROWS/4, blk, 0, stream>>>(x, norm_w + i*D_MODEL, xn_b);
        // in_proj: 8192 x 1536 x 384
        gemm_mfma<0><<<dim3(12, 64), blk, 0, stream>>>(
            xn_b, D_MODEL, inw_b + (size_t)i*2*D_INNER*D_MODEL, D_MODEL,
            xz, 2*D_INNER, nullptr, nullptr, 2*D_INNER, D_MODEL);
        // conv + silu -> xin f32 + bf16
        conv_silu_k<<<ROWS*D_INNER/256, blk, 0, stream>>>(
            xz, conv_w + i*D_INNER*D_CONV, conv_b + i*D_INNER, xin, xin_b);
        // x_proj: 8192 x 56 x 768 (padded to 128 cols) -> proj f32 + bf16
        gemm_mfma<3><<<dim3(1, 64), blk, 0, stream>>>(
            xin_b, D_INNER, xpw_b + (size_t)i*128*D_INNER, D_INNER,
            proj, 56, proj_b, nullptr, 56, D_INNER);
        // dt_proj + softplus: 8192 x 768 x 24 (K padded to 32)
        gemm_mfma<1><<<dim3(6, 64), blk, 0, stream>>>(
            proj_b, 56, dtw_b + (size_t)i*D_INNER*32, 32,
            dtf, D_INNER, nullptr, dt_proj_b + i*D_INNER, D_INNER, 32);
        // chunked selective scan
        scan_p1<<<dim3(48, NCHUNK, BATCH), blk, 0, stream>>>(
            dtf, xin, proj, A_log + (size_t)i*D_INNER*D_STATE, h_end, decay);
        scan_p2<<<BATCH*D_INNER*D_STATE/256, blk, 0, stream>>>(h_end, decay, h_init);
        scan_p3<<<dim3(48, NCHUNK, BATCH), blk, 0, stream>>>(
            dtf, xin, xz, proj, A_log + (size_t)i*D_INNER*D_STATE,
            D_param + i*D_INNER, h_init, y_b);
        // out_proj + residual: 8192 x 384 x 768, x += ...
        gemm_mfma<2><<<dim3(3, 64), blk, 0, stream>>>(
            y_b, D_INNER, outw_b + (size_t)i*D_MODEL*D_INNER, D_INNER,
            x, D_MODEL, nullptr, nullptr, D_MODEL, D_INNER);
    }

    rmsnorm_k<<<ROWS/4, blk, 0, stream>>>(x, final_norm_w, xn_b);
    // lm_head: 8192 x 5000 x 384
    gemm_mfma<0><<<dim3(40, 64), blk, 0, stream>>>(
        xn_b, D_MODEL, emb_b, D_MODEL, out, VOCAB, nullptr, nullptr, VOCAB, D_MODEL);
}

// Round 5
// 1415.736 us; speedup vs baseline: 4.1140x; 1.1175x over previous
//
#include <hip/hip_runtime.h>
#include <hip/hip_bf16.h>

#define D_MODEL 384
#define N_LAYER 4
#define VOCAB   5000
#define D_INNER 768
#define D_STATE 16
#define DT_RANK 24
#define D_CONV  4
#define BATCH   4
#define SEQ     2048
#define ROWS    (BATCH*SEQ)          // 8192
#define NCHUNK  64
#define CLEN    32                   // NCHUNK*CLEN == SEQ

typedef __attribute__((ext_vector_type(8))) short bf16x8;
typedef __attribute__((ext_vector_type(4))) float f32x4;

// fp32 -> bf16 (RNE), finite inputs only
static __device__ __forceinline__ ushort f2b(float f) {
    uint u = __float_as_uint(f);
    return (ushort)((u + 0x7FFFu + ((u >> 16) & 1u)) >> 16);
}

// ---------------------------------------------------------------- fp32->bf16 bulk
__global__ __launch_bounds__(256)
void f2b_k(const float* __restrict__ in, ushort* __restrict__ out, int n4)
{
    int i = blockIdx.x * 256 + threadIdx.x;
    if (i < n4) {
        float4 v = reinterpret_cast<const float4*>(in)[i];
        ushort4 o;
        o.x = f2b(v.x); o.y = f2b(v.y); o.z = f2b(v.z); o.w = f2b(v.w);
        reinterpret_cast<ushort4*>(out)[i] = o;
    }
}

// pad x_proj_w [4][56][768] -> bf16 [4][128][768] (rows 56..127 zero)
__global__ __launch_bounds__(256)
void pad_xpw(const float* __restrict__ w, ushort* __restrict__ o)
{
    int i = blockIdx.x * 256 + threadIdx.x;          // 4*128*768
    int l = i / (128*768); int rk = i % (128*768);
    int r = rk / 768, k = rk % 768;
    float v = (r < 56) ? w[((size_t)l*56 + r)*768 + k] : 0.f;
    o[i] = f2b(v);
}

// pad dt_proj_w [4][768][24] -> bf16 [4][768][32] (k 24..31 zero)
__global__ __launch_bounds__(256)
void pad_dtw(const float* __restrict__ w, ushort* __restrict__ o)
{
    int i = blockIdx.x * 256 + threadIdx.x;          // 4*768*32
    int l = i / (768*32); int ek = i % (768*32);
    int e = ek / 32, k = ek % 32;
    float v = (k < 24) ? w[((size_t)l*768 + e)*24 + k] : 0.f;
    o[i] = f2b(v);
}

// ---------------------------------------------------------------- embed gather
__global__ __launch_bounds__(256)
void embed_gather(const int* __restrict__ tokens, const float* __restrict__ embed,
                  float* __restrict__ x)
{
    int idx = blockIdx.x * 256 + threadIdx.x;       // ROWS * 96 float4s
    int row = idx / 96, c4 = idx % 96;
    int tok = tokens[row];
    reinterpret_cast<float4*>(x)[(size_t)row * 96 + c4] =
        reinterpret_cast<const float4*>(embed)[(size_t)tok * 96 + c4];
}

// ---------------------------------------------------------------- rmsnorm -> bf16
__global__ __launch_bounds__(256)
void rmsnorm_k(const float* __restrict__ xin, const float* __restrict__ w,
               ushort* __restrict__ xout)
{
    int row  = blockIdx.x * 4 + (threadIdx.x >> 6);
    int lane = threadIdx.x & 63;
    const float* xr = xin + (size_t)row * D_MODEL;
    float v[6]; float ss = 0.f;
    #pragma unroll
    for (int j = 0; j < 6; ++j) { v[j] = xr[lane + 64*j]; ss += v[j]*v[j]; }
    #pragma unroll
    for (int m = 32; m; m >>= 1) ss += __shfl_xor(ss, m, 64);
    float r = rsqrtf(ss * (1.f/D_MODEL) + 1e-5f);
    ushort* yo = xout + (size_t)row * D_MODEL;
    #pragma unroll
    for (int j = 0; j < 6; ++j) yo[lane + 64*j] = f2b(v[j] * w[lane + 64*j] * r);
}

// ---------------------------------------------------------------- conv1d + silu
__global__ __launch_bounds__(256)
void conv_silu_k(const float* __restrict__ xz, const float* __restrict__ cw,
                 const float* __restrict__ cb, float* __restrict__ xout,
                 ushort* __restrict__ xout_b)
{
    int idx = blockIdx.x * 256 + threadIdx.x;       // ROWS * D_INNER
    int e   = idx % D_INNER;
    int row = idx / D_INNER;
    int l   = row & (SEQ - 1);
    float acc = cb[e];
    #pragma unroll
    for (int j = 0; j < 4; ++j) {
        if (l - j >= 0)
            acc += cw[e*4 + 3 - j] * xz[(size_t)(row - j) * (2*D_INNER) + e];
    }
    float s = acc / (1.f + __expf(-acc));           // silu
    xout[idx]   = s;
    xout_b[idx] = f2b(s);
}

// ---------------------------------------------------------------- bf16 MFMA GEMM
// C[M,N](f32) = A[M,K](bf16) @ B[N,K](bf16)^T.
// EPI: 0 store | 1 softplus(v+bias[col]) | 2 C+= | 3 store f32 + bf16 copy.
// Requires K%32==0, M%128==0; B rows readable up to col rounded up to 128.
template<int EPI>
__global__ __launch_bounds__(256)
void gemm_mfma(const ushort* __restrict__ A, int lda,
               const ushort* __restrict__ B, int ldb,
               float* __restrict__ C, int ldc,
               ushort* __restrict__ Cb, const float* __restrict__ bias,
               int N, int K)
{
    int wave = threadIdx.x >> 6;
    int lane = threadIdx.x & 63;
    int wr = wave >> 1, wc = wave & 1;              // 2x2 waves -> 128x128 block
    int row0 = blockIdx.y * 128 + wr * 64;
    int col0 = blockIdx.x * 128 + wc * 64;
    int l15 = lane & 15, g = lane >> 4;             // g selects k-group of 8

    f32x4 acc[4][4] = {};
    for (int k0 = 0; k0 < K; k0 += 32) {
        bf16x8 af[4], bf_[4];
        int ka = k0 + g * 8;
        #pragma unroll
        for (int i = 0; i < 4; ++i)
            af[i] = *reinterpret_cast<const bf16x8*>(&A[(size_t)(row0 + i*16 + l15) * lda + ka]);
        #pragma unroll
        for (int j = 0; j < 4; ++j)
            bf_[j] = *reinterpret_cast<const bf16x8*>(&B[(size_t)(col0 + j*16 + l15) * ldb + ka]);
        #pragma unroll
        for (int i = 0; i < 4; ++i)
            #pragma unroll
            for (int j = 0; j < 4; ++j)
                acc[i][j] = __builtin_amdgcn_mfma_f32_16x16x32_bf16(af[i], bf_[j], acc[i][j], 0, 0, 0);
    }

    // C/D layout: col = lane&15, row = (lane>>4)*4 + reg
    #pragma unroll
    for (int i = 0; i < 4; ++i) {
        int r = row0 + i*16 + g*4;
        #pragma unroll
        for (int j = 0; j < 4; ++j) {
            int c = col0 + j*16 + l15;
            if (c < N) {
                #pragma unroll
                for (int rr = 0; rr < 4; ++rr) {
                    float v = acc[i][j][rr];
                    size_t off = (size_t)(r + rr) * ldc + c;
                    if (EPI == 1) {
                        v += bias[c];
                        v = fmaxf(v, 0.f) + log1pf(__expf(-fabsf(v)));   // softplus
                        C[off] = v;
                    } else if (EPI == 2) {
                        C[off] += v;
                    } else {
                        C[off] = v;
                        if (EPI == 3) Cb[off] = f2b(v);
                    }
                }
            }
        }
    }
}

// ---------------------------------------------------------------- chunked scan
// Thread <-> (b, chunk, e); all 16 states in registers.
// h_end/decay/h_init layout: [b][e][n][c]  (c innermost, NCHUNK=64)

// Pass 1: local scan from h=0 -> h_end, decay = exp(a*sum(dt))
__global__ __launch_bounds__(256)
void scan_p1(const float* __restrict__ dtf, const float* __restrict__ xin,
             const float* __restrict__ proj, const float* __restrict__ A_log,
             float* __restrict__ h_end, float* __restrict__ decay)
{
    __shared__ float Bs[CLEN][16];                  // 2 KB
    int b = blockIdx.z, c = blockIdx.y;
    int e = blockIdx.x * 256 + threadIdx.x;
    size_t r0 = (size_t)b * SEQ + (size_t)c * CLEN;

    for (int i = threadIdx.x; i < CLEN*16; i += 256) {
        int l = i >> 4, n = i & 15;
        Bs[l][n] = proj[(r0 + l) * 56 + DT_RANK + n];
    }
    __syncthreads();

    float a[16];
    const float4* ap = reinterpret_cast<const float4*>(A_log + e * D_STATE);
    #pragma unroll
    for (int q = 0; q < 4; ++q) {
        float4 av = ap[q];
        a[q*4+0] = -__expf(av.x); a[q*4+1] = -__expf(av.y);
        a[q*4+2] = -__expf(av.z); a[q*4+3] = -__expf(av.w);
    }

    const float* pdt = dtf + r0 * D_INNER + e;
    const float* px  = xin + r0 * D_INNER + e;
    float h[16];
    #pragma unroll
    for (int n = 0; n < 16; ++n) h[n] = 0.f;
    float S = 0.f;
    float dtv = pdt[0], xv = px[0];

    for (int l = 0; l < CLEN; ++l) {
        float dtn = 0.f, xn2 = 0.f;
        if (l + 1 < CLEN) {
            dtn = pdt[(size_t)(l+1) * D_INNER];
            xn2 = px [(size_t)(l+1) * D_INNER];
        }
        float dtx = dtv * xv;
        S += dtv;
        const float4* br = reinterpret_cast<const float4*>(&Bs[l][0]);
        float4 B0 = br[0], B1 = br[1], B2 = br[2], B3 = br[3];
        float Bv[16] = {B0.x,B0.y,B0.z,B0.w, B1.x,B1.y,B1.z,B1.w,
                        B2.x,B2.y,B2.z,B2.w, B3.x,B3.y,B3.z,B3.w};
        #pragma unroll
        for (int n = 0; n < 16; ++n) {
            float ex = __expf(dtv * a[n]);
            h[n] = h[n] * ex + dtx * Bv[n];
        }
        dtv = dtn; xv = xn2;
    }

    size_t base = (((size_t)b * D_INNER + e) * D_STATE) * NCHUNK + c;
    #pragma unroll
    for (int n = 0; n < 16; ++n) {
        h_end[base + (size_t)n * NCHUNK] = h[n];
        decay[base + (size_t)n * NCHUNK] = __expf(a[n] * S);
    }
}

// Pass 2: wave-parallel (Hillis-Steele) chunk combine. One wave per (b,e,n);
// lane = chunk. Pair (d,v): h_out = v + d*h_in; compose left-to-right.
__global__ __launch_bounds__(256)
void scan_p2(const float* __restrict__ h_end, const float* __restrict__ decay,
             float* __restrict__ h_init)
{
    int wid  = (blockIdx.x * 256 + threadIdx.x) >> 6;   // (b,e,n) flat
    int lane = threadIdx.x & 63;
    size_t base = (size_t)wid * NCHUNK;
    float d = decay[base + lane];
    float v = h_end[base + lane];
    #pragma unroll
    for (int off = 1; off < 64; off <<= 1) {
        float dp = __shfl_up(d, off, 64);
        float vp = __shfl_up(v, off, 64);
        if (lane >= off) { v = fmaf(d, vp, v); d *= dp; }
    }
    float hi = __shfl_up(v, 1, 64);
    if (lane == 0) hi = 0.f;
    h_init[base + lane] = hi;
}

// Pass 3: re-scan each chunk from h_init; y + D-skip + gate -> bf16
__global__ __launch_bounds__(256)
void scan_p3(const float* __restrict__ dtf, const float* __restrict__ xin,
             const float* __restrict__ xz, const float* __restrict__ proj,
             const float* __restrict__ A_log, const float* __restrict__ Dp,
             const float* __restrict__ h_init, ushort* __restrict__ y)
{
    __shared__ float BCs[CLEN][32];                 // 4 KB (B:0..15, C:16..31)
    int b = blockIdx.z, c = blockIdx.y;
    int e = blockIdx.x * 256 + threadIdx.x;
    size_t r0 = (size_t)b * SEQ + (size_t)c * CLEN;

    for (int i = threadIdx.x; i < CLEN*32; i += 256) {
        int l = i >> 5, r = i & 31;
        BCs[l][r] = proj[(r0 + l) * 56 + DT_RANK + r];
    }
    __syncthreads();

    float a[16];
    const float4* ap = reinterpret_cast<const float4*>(A_log + e * D_STATE);
    #pragma unroll
    for (int q = 0; q < 4; ++q) {
        float4 av = ap[q];
        a[q*4+0] = -__expf(av.x); a[q*4+1] = -__expf(av.y);
        a[q*4+2] = -__expf(av.z); a[q*4+3] = -__expf(av.w);
    }
    float dskip = Dp[e];

    float h[16];
    size_t hbase = (((size_t)b * D_INNER + e) * D_STATE) * NCHUNK + c;
    #pragma unroll
    for (int n = 0; n < 16; ++n) h[n] = h_init[hbase + (size_t)n * NCHUNK];

    const float* pdt = dtf + r0 * D_INNER + e;
    const float* px  = xin + r0 * D_INNER + e;
    const float* pz  = xz  + r0 * (2*D_INNER) + D_INNER + e;
    ushort*      py  = y   + r0 * D_INNER + e;

    float dtv = pdt[0], xv = px[0], zv = pz[0];

    for (int l = 0; l < CLEN; ++l) {
        float dtn = 0.f, xn2 = 0.f, zn = 0.f;
        if (l + 1 < CLEN) {
            dtn = pdt[(size_t)(l+1) * D_INNER];
            xn2 = px [(size_t)(l+1) * D_INNER];
            zn  = pz [(size_t)(l+1) * (2*D_INNER)];
        }
        float dtx = dtv * xv;
        const float4* br = reinterpret_cast<const float4*>(&BCs[l][0]);
        float4 B0 = br[0], B1 = br[1], B2 = br[2], B3 = br[3];
        float Bv[16] = {B0.x,B0.y,B0.z,B0.w, B1.x,B1.y,B1.z,B1.w,
                        B2.x,B2.y,B2.z,B2.w, B3.x,B3.y,B3.z,B3.w};
        #pragma unroll
        for (int n = 0; n < 16; ++n) {
            float ex = __expf(dtv * a[n]);
            h[n] = h[n] * ex + dtx * Bv[n];
        }
        float4 C0 = br[4], C1 = br[5], C2 = br[6], C3 = br[7];
        float Cv[16] = {C0.x,C0.y,C0.z,C0.w, C1.x,C1.y,C1.z,C1.w,
                        C2.x,C2.y,C2.z,C2.w, C3.x,C3.y,C3.z,C3.w};
        float yv = 0.f;
        #pragma unroll
        for (int n = 0; n < 16; ++n) yv += h[n] * Cv[n];

        float g = zv / (1.f + __expf(-zv));         // silu(z)
        py[(size_t)l * D_INNER] = f2b((yv + xv * dskip) * g);

        dtv = dtn; xv = xn2; zv = zn;
    }
}

// ---------------------------------------------------------------- launch
extern "C" void kernel_launch(void* const* d_in, const int* in_sizes, int n_in,
                              void* d_out, int out_size, void* d_ws, size_t ws_size,
                              hipStream_t stream)
{
    const int*   tokens       = (const int*)  d_in[0];
    const float* embed        = (const float*)d_in[1];
    const float* norm_w       = (const float*)d_in[2];
    const float* in_proj_w    = (const float*)d_in[3];
    const float* conv_w       = (const float*)d_in[4];
    const float* conv_b       = (const float*)d_in[5];
    const float* x_proj_w     = (const float*)d_in[6];
    const float* dt_proj_w    = (const float*)d_in[7];
    const float* dt_proj_b    = (const float*)d_in[8];
    const float* A_log        = (const float*)d_in[9];
    const float* D_param      = (const float*)d_in[10];
    const float* out_proj_w   = (const float*)d_in[11];
    const float* final_norm_w = (const float*)d_in[12];
    float* out = (float*)d_out;

    // ---- workspace map (float offsets), ~33.6 MB
    float* ws = (float*)d_ws;
    float*  x      = ws;                          // 3,145,728
    float*  proj   = ws + 3145728;                // 458,752
    ushort* xn_b   = (ushort*)(ws + 3604480);     // 3,145,728 us
    ushort* inw_b  = (ushort*)(ws + 5177344);     // 2,359,296 us
    ushort* outw_b = (ushort*)(ws + 6356992);     // 1,179,648 us
    ushort* emb_b  = (ushort*)(ws + 6946816);     // 5120*384 us (rows>=5000: junk, cols discarded)
    ushort* xpw_b  = (ushort*)(ws + 7929856);     // 4*128*768 us
    ushort* dtw_b  = (ushort*)(ws + 8126464);     // 4*768*32 us
    ushort* proj_b = (ushort*)(ws + 8175616);     // 8192*56 us -> ends 8,404,992

    // ---- big scratch in d_out (40,960,000 floats; all dead before lm_head)
    float*  xz     = out;                         //  0 .. 12,582,912
    float*  xin    = out + 12582912;              // .. 18,874,368
    float*  dtf    = out + 18874368;              // .. 25,165,824
    ushort* y_b    = (ushort*)(out + 25165824);   // .. 28,311,552 (6,291,456 us)
    ushort* xin_b  = (ushort*)(out + 28311552);   // .. 31,457,280 (6,291,456 us)
    float*  h_end  = out + 31457280;              // .. 34,603,008
    float*  decay  = out + 34603008;              // .. 37,748,736
    float*  h_init = out + 37748736;              // .. 40,894,464 (< 40,960,000)

    dim3 blk(256);

    // one-shot weight conversions
    f2b_k<<<(N_LAYER*2*D_INNER*D_MODEL/4 + 255)/256, blk, 0, stream>>>(in_proj_w,  inw_b,  N_LAYER*2*D_INNER*D_MODEL/4);
    f2b_k<<<(N_LAYER*D_MODEL*D_INNER/4  + 255)/256, blk, 0, stream>>>(out_proj_w, outw_b, N_LAYER*D_MODEL*D_INNER/4);
    f2b_k<<<(VOCAB*D_MODEL/4            + 255)/256, blk, 0, stream>>>(embed,      emb_b,  VOCAB*D_MODEL/4);
    pad_xpw<<<N_LAYER*128*768/256, blk, 0, stream>>>(x_proj_w, xpw_b);
    pad_dtw<<<N_LAYER*768*32/256,  blk, 0, stream>>>(dt_proj_w, dtw_b);

    embed_gather<<<ROWS*96/256, blk, 0, stream>>>(tokens, embed, x);

    for (int i = 0; i < N_LAYER; ++i) {
        rmsnorm_k<<<ROWS/4, blk, 0, stream>>>(x, norm_w + i*D_MODEL, xn_b);
        // in_proj: 8192 x 1536 x 384
        gemm_mfma<0><<<dim3(12, 64), blk, 0, stream>>>(
            xn_b, D_MODEL, inw_b + (size_t)i*2*D_INNER*D_MODEL, D_MODEL,
            xz, 2*D_INNER, nullptr, nullptr, 2*D_INNER, D_MODEL);
        // conv + silu -> xin f32 + bf16
        conv_silu_k<<<ROWS*D_INNER/256, blk, 0, stream>>>(
            xz, conv_w + i*D_INNER*D_CONV, conv_b + i*D_INNER, xin, xin_b);
        // x_proj: 8192 x 56 x 768 (padded to 128 cols) -> proj f32 + bf16
        gemm_mfma<3><<<dim3(1, 64), blk, 0, stream>>>(
            xin_b, D_INNER, xpw_b + (size_t)i*128*D_INNER, D_INNER,
            proj, 56, proj_b, nullptr, 56, D_INNER);
        // dt_proj + softplus: 8192 x 768 x 24 (K padded to 32)
        gemm_mfma<1><<<dim3(6, 64), blk, 0, stream>>>(
            proj_b, 56, dtw_b + (size_t)i*D_INNER*32, 32,
            dtf, D_INNER, nullptr, dt_proj_b + i*D_INNER, D_INNER, 32);
        // chunked selective scan (register-state layout)
        scan_p1<<<dim3(3, NCHUNK, BATCH), blk, 0, stream>>>(
            dtf, xin, proj, A_log + (size_t)i*D_INNER*D_STATE, h_end, decay);
        scan_p2<<<BATCH*D_INNER*D_STATE/4, blk, 0, stream>>>(h_end, decay, h_init);
        scan_p3<<<dim3(3, NCHUNK, BATCH), blk, 0, stream>>>(
            dtf, xin, xz, proj, A_log + (size_t)i*D_INNER*D_STATE,
            D_param + i*D_INNER, h_init, y_b);
        // out_proj + residual: 8192 x 384 x 768, x += ...
        gemm_mfma<2><<<dim3(3, 64), blk, 0, stream>>>(
            y_b, D_INNER, outw_b + (size_t)i*D_MODEL*D_INNER, D_INNER,
            x, D_MODEL, nullptr, nullptr, D_MODEL, D_INNER);
    }

    rmsnorm_k<<<ROWS/4, blk, 0, stream>>>(x, final_norm_w, xn_b);
    // lm_head: 8192 x 5000 x 384 (overwrites ALL of d_out)
    gemm_mfma<0><<<dim3(40, 64), blk, 0, stream>>>(
        xn_b, D_MODEL, emb_b, D_MODEL, out, VOCAB, nullptr, nullptr, VOCAB, D_MODEL);
}

// Round 6
// 1164.940 us; speedup vs baseline: 4.9996x; 1.2153x over previous
//
#include <hip/hip_runtime.h>
#include <hip/hip_bf16.h>

#define D_MODEL 384
#define N_LAYER 4
#define VOCAB   5000
#define D_INNER 768
#define D_STATE 16
#define DT_RANK 24
#define D_CONV  4
#define BATCH   4
#define SEQ     2048
#define ROWS    (BATCH*SEQ)          // 8192
#define NCHUNK  64
#define CLEN    32                   // NCHUNK*CLEN == SEQ

typedef __attribute__((ext_vector_type(8))) short bf16x8;
typedef __attribute__((ext_vector_type(4))) float f32x4;

// fp32 -> bf16 (RNE), finite inputs only
static __device__ __forceinline__ ushort f2b(float f) {
    uint u = __float_as_uint(f);
    return (ushort)((u + 0x7FFFu + ((u >> 16) & 1u)) >> 16);
}
static __device__ __forceinline__ float b2f(ushort u) {
    return __uint_as_float((uint)u << 16);
}

// async global->LDS, 16B per lane (dst = wave base + lane*16, linear)
static __device__ __forceinline__ void gl_lds16(const void* g, void* l) {
    __builtin_amdgcn_global_load_lds(
        (const __attribute__((address_space(1))) void*)g,
        (__attribute__((address_space(3))) void*)l, 16, 0, 0);
}

// ---------------------------------------------------------------- fp32->bf16 bulk
__global__ __launch_bounds__(256)
void f2b_k(const float* __restrict__ in, ushort* __restrict__ out, int n4)
{
    int i = blockIdx.x * 256 + threadIdx.x;
    if (i < n4) {
        float4 v = reinterpret_cast<const float4*>(in)[i];
        ushort4 o;
        o.x = f2b(v.x); o.y = f2b(v.y); o.z = f2b(v.z); o.w = f2b(v.w);
        reinterpret_cast<ushort4*>(out)[i] = o;
    }
}

// pad x_proj_w [4][56][768] -> bf16 [4][128][768] (rows 56..127 zero)
__global__ __launch_bounds__(256)
void pad_xpw(const float* __restrict__ w, ushort* __restrict__ o)
{
    int i = blockIdx.x * 256 + threadIdx.x;          // 4*128*768
    int l = i / (128*768); int rk = i % (128*768);
    int r = rk / 768, k = rk % 768;
    float v = (r < 56) ? w[((size_t)l*56 + r)*768 + k] : 0.f;
    o[i] = f2b(v);
}

// pad dt_proj_w [4][768][24] -> bf16 [4][768][32] (k 24..31 zero)
__global__ __launch_bounds__(256)
void pad_dtw(const float* __restrict__ w, ushort* __restrict__ o)
{
    int i = blockIdx.x * 256 + threadIdx.x;          // 4*768*32
    int l = i / (768*32); int ek = i % (768*32);
    int e = ek / 32, k = ek % 32;
    float v = (k < 24) ? w[((size_t)l*768 + e)*24 + k] : 0.f;
    o[i] = f2b(v);
}

// ---------------------------------------------------------------- embed gather
__global__ __launch_bounds__(256)
void embed_gather(const int* __restrict__ tokens, const float* __restrict__ embed,
                  float* __restrict__ x)
{
    int idx = blockIdx.x * 256 + threadIdx.x;       // ROWS * 96 float4s
    int row = idx / 96, c4 = idx % 96;
    int tok = tokens[row];
    reinterpret_cast<float4*>(x)[(size_t)row * 96 + c4] =
        reinterpret_cast<const float4*>(embed)[(size_t)tok * 96 + c4];
}

// ---------------------------------------------------------------- rmsnorm -> bf16
__global__ __launch_bounds__(256)
void rmsnorm_k(const float* __restrict__ xin, const float* __restrict__ w,
               ushort* __restrict__ xout)
{
    int row  = blockIdx.x * 4 + (threadIdx.x >> 6);
    int lane = threadIdx.x & 63;
    const float* xr = xin + (size_t)row * D_MODEL;
    float v[6]; float ss = 0.f;
    #pragma unroll
    for (int j = 0; j < 6; ++j) { v[j] = xr[lane + 64*j]; ss += v[j]*v[j]; }
    #pragma unroll
    for (int m = 32; m; m >>= 1) ss += __shfl_xor(ss, m, 64);
    float r = rsqrtf(ss * (1.f/D_MODEL) + 1e-5f);
    ushort* yo = xout + (size_t)row * D_MODEL;
    #pragma unroll
    for (int j = 0; j < 6; ++j) yo[lane + 64*j] = f2b(v[j] * w[lane + 64*j] * r);
}

// ---------------------------------------------------------------- conv1d + silu -> bf16
__global__ __launch_bounds__(256)
void conv_silu_k(const float* __restrict__ xz, const float* __restrict__ cw,
                 const float* __restrict__ cb, ushort* __restrict__ xout_b)
{
    int idx = blockIdx.x * 256 + threadIdx.x;       // ROWS * D_INNER
    int e   = idx % D_INNER;
    int row = idx / D_INNER;
    int l   = row & (SEQ - 1);
    float acc = cb[e];
    #pragma unroll
    for (int j = 0; j < 4; ++j) {
        if (l - j >= 0)
            acc += cw[e*4 + 3 - j] * xz[(size_t)(row - j) * (2*D_INNER) + e];
    }
    float s = acc / (1.f + __expf(-acc));           // silu
    xout_b[idx] = f2b(s);
}

// ---------------------------------------------------------------- LDS-staged MFMA GEMM
// C[M,N](f32) = A[M,K](bf16) @ B[N,K](bf16)^T, m97-style structure.
// Tile TM x TN, BK=32. 4 waves as 2x2. XOR-swizzled LDS (slot ^= (row>>1)&3),
// applied on the GLOBAL source (LDS dest linear, as global_load_lds requires)
// and on the ds_read offset.
// EPI: 0 store | 1 softplus(v+bias[col]) | 2 C+= | 3 store f32 + bf16 copy.
// Requires K%32==0, M%TM==0; B rows readable up to col0+TN (padded).
template<int TM, int TN, int EPI>
__global__ __launch_bounds__(256)
void gemm_lds(const ushort* __restrict__ A, int lda,
              const ushort* __restrict__ B, int ldb,
              float* __restrict__ C, int ldc,
              ushort* __restrict__ Cb, const float* __restrict__ bias,
              int N, int K)
{
    constexpr int FM = TM / 32, FN = TN / 32;       // frags per wave
    __shared__ ushort As[TM * 32];
    __shared__ ushort Bs[TN * 32];
    int tid = threadIdx.x, w = tid >> 6, l = tid & 63;
    int wr = w >> 1, wc = w & 1;
    int row0 = blockIdx.y * TM, col0 = blockIdx.x * TN;
    int l15 = l & 15, g = l >> 4;
    int sr = l >> 2, sp = l & 3;                    // staging row-in-inst, phys slot

    f32x4 acc[FM][FN] = {};

    for (int k0 = 0; k0 < K; k0 += 32) {
        // stage A (TM/64 insts per wave; each inst = 16 rows x 32 cols)
        #pragma unroll
        for (int j = 0; j < TM/64; ++j) {
            int ai = w * (TM/64) + j;
            int r  = ai * 16 + sr;
            int s  = sp ^ ((r >> 1) & 3);           // logical slot this lane fetches
            gl_lds16(&A[(size_t)(row0 + r) * lda + k0 + s*8], &As[ai * 512]);
        }
        #pragma unroll
        for (int j = 0; j < TN/64; ++j) {
            int bi = w * (TN/64) + j;
            int r  = bi * 16 + sr;
            int s  = sp ^ ((r >> 1) & 3);
            gl_lds16(&B[(size_t)(col0 + r) * ldb + k0 + s*8], &Bs[bi * 512]);
        }
        __syncthreads();

        bf16x8 af[FM], bfr[FN];
        #pragma unroll
        for (int i = 0; i < FM; ++i) {
            int r = wr * (TM/2) + i*16 + l15;
            int p = g ^ ((r >> 1) & 3);
            af[i] = *reinterpret_cast<const bf16x8*>(&As[r*32 + p*8]);
        }
        #pragma unroll
        for (int i = 0; i < FN; ++i) {
            int r = wc * (TN/2) + i*16 + l15;
            int p = g ^ ((r >> 1) & 3);
            bfr[i] = *reinterpret_cast<const bf16x8*>(&Bs[r*32 + p*8]);
        }
        #pragma unroll
        for (int i = 0; i < FM; ++i)
            #pragma unroll
            for (int jj = 0; jj < FN; ++jj)
                acc[i][jj] = __builtin_amdgcn_mfma_f32_16x16x32_bf16(af[i], bfr[jj], acc[i][jj], 0, 0, 0);
        __syncthreads();
    }

    // C/D layout: col = lane&15, row = (lane>>4)*4 + reg
    #pragma unroll
    for (int i = 0; i < FM; ++i) {
        int r = row0 + wr * (TM/2) + i*16 + g*4;
        #pragma unroll
        for (int jj = 0; jj < FN; ++jj) {
            int c = col0 + wc * (TN/2) + jj*16 + l15;
            if (c < N) {
                #pragma unroll
                for (int rr = 0; rr < 4; ++rr) {
                    float v = acc[i][jj][rr];
                    size_t off = (size_t)(r + rr) * ldc + c;
                    if (EPI == 1) {
                        v += bias[c];
                        v = fmaxf(v, 0.f) + log1pf(__expf(-fabsf(v)));   // softplus
                        C[off] = v;
                    } else if (EPI == 2) {
                        C[off] += v;
                    } else {
                        C[off] = v;
                        if (EPI == 3) Cb[off] = f2b(v);
                    }
                }
            }
        }
    }
}

// ---------------------------------------------------------------- chunked scan
// Thread <-> (b, chunk, e); all 16 states in registers.
// h_end/decay/h_init layout: [b][e][n][c]  (c innermost, NCHUNK=64)

// Pass 1: local scan from h=0 -> h_end, decay = exp(a*sum(dt))
__global__ __launch_bounds__(256)
void scan_p1(const float* __restrict__ dtf, const ushort* __restrict__ xin_b,
             const float* __restrict__ proj, const float* __restrict__ A_log,
             float* __restrict__ h_end, float* __restrict__ decay)
{
    __shared__ float Bs[CLEN][16];                  // 2 KB
    int b = blockIdx.z, c = blockIdx.y;
    int e = blockIdx.x * 256 + threadIdx.x;
    size_t r0 = (size_t)b * SEQ + (size_t)c * CLEN;

    for (int i = threadIdx.x; i < CLEN*16; i += 256) {
        int l = i >> 4, n = i & 15;
        Bs[l][n] = proj[(r0 + l) * 56 + DT_RANK + n];
    }
    __syncthreads();

    float a[16];
    const float4* ap = reinterpret_cast<const float4*>(A_log + e * D_STATE);
    #pragma unroll
    for (int q = 0; q < 4; ++q) {
        float4 av = ap[q];
        a[q*4+0] = -__expf(av.x); a[q*4+1] = -__expf(av.y);
        a[q*4+2] = -__expf(av.z); a[q*4+3] = -__expf(av.w);
    }

    const float*  pdt = dtf   + r0 * D_INNER + e;
    const ushort* px  = xin_b + r0 * D_INNER + e;
    float h[16];
    #pragma unroll
    for (int n = 0; n < 16; ++n) h[n] = 0.f;
    float S = 0.f;
    float dtv = pdt[0], xv = b2f(px[0]);

    for (int l = 0; l < CLEN; ++l) {
        float dtn = 0.f, xn2 = 0.f;
        if (l + 1 < CLEN) {
            dtn = pdt[(size_t)(l+1) * D_INNER];
            xn2 = b2f(px[(size_t)(l+1) * D_INNER]);
        }
        float dtx = dtv * xv;
        S += dtv;
        const float4* br = reinterpret_cast<const float4*>(&Bs[l][0]);
        float4 B0 = br[0], B1 = br[1], B2 = br[2], B3 = br[3];
        float Bv[16] = {B0.x,B0.y,B0.z,B0.w, B1.x,B1.y,B1.z,B1.w,
                        B2.x,B2.y,B2.z,B2.w, B3.x,B3.y,B3.z,B3.w};
        #pragma unroll
        for (int n = 0; n < 16; ++n) {
            float ex = __expf(dtv * a[n]);
            h[n] = h[n] * ex + dtx * Bv[n];
        }
        dtv = dtn; xv = xn2;
    }

    size_t base = (((size_t)b * D_INNER + e) * D_STATE) * NCHUNK + c;
    #pragma unroll
    for (int n = 0; n < 16; ++n) {
        h_end[base + (size_t)n * NCHUNK] = h[n];
        decay[base + (size_t)n * NCHUNK] = __expf(a[n] * S);
    }
}

// Pass 2: wave-parallel (Hillis-Steele) chunk combine. One wave per (b,e,n);
// lane = chunk. Pair (d,v): h_out = v + d*h_in; compose left-to-right.
__global__ __launch_bounds__(256)
void scan_p2(const float* __restrict__ h_end, const float* __restrict__ decay,
             float* __restrict__ h_init)
{
    int wid  = (blockIdx.x * 256 + threadIdx.x) >> 6;   // (b,e,n) flat
    int lane = threadIdx.x & 63;
    size_t base = (size_t)wid * NCHUNK;
    float d = decay[base + lane];
    float v = h_end[base + lane];
    #pragma unroll
    for (int off = 1; off < 64; off <<= 1) {
        float dp = __shfl_up(d, off, 64);
        float vp = __shfl_up(v, off, 64);
        if (lane >= off) { v = fmaf(d, vp, v); d *= dp; }
    }
    float hi = __shfl_up(v, 1, 64);
    if (lane == 0) hi = 0.f;
    h_init[base + lane] = hi;
}

// Pass 3: re-scan each chunk from h_init; y + D-skip + gate -> bf16
__global__ __launch_bounds__(256)
void scan_p3(const float* __restrict__ dtf, const ushort* __restrict__ xin_b,
             const float* __restrict__ xz, const float* __restrict__ proj,
             const float* __restrict__ A_log, const float* __restrict__ Dp,
             const float* __restrict__ h_init, ushort* __restrict__ y)
{
    __shared__ float BCs[CLEN][32];                 // 4 KB (B:0..15, C:16..31)
    int b = blockIdx.z, c = blockIdx.y;
    int e = blockIdx.x * 256 + threadIdx.x;
    size_t r0 = (size_t)b * SEQ + (size_t)c * CLEN;

    for (int i = threadIdx.x; i < CLEN*32; i += 256) {
        int l = i >> 5, r = i & 31;
        BCs[l][r] = proj[(r0 + l) * 56 + DT_RANK + r];
    }
    __syncthreads();

    float a[16];
    const float4* ap = reinterpret_cast<const float4*>(A_log + e * D_STATE);
    #pragma unroll
    for (int q = 0; q < 4; ++q) {
        float4 av = ap[q];
        a[q*4+0] = -__expf(av.x); a[q*4+1] = -__expf(av.y);
        a[q*4+2] = -__expf(av.z); a[q*4+3] = -__expf(av.w);
    }
    float dskip = Dp[e];

    float h[16];
    size_t hbase = (((size_t)b * D_INNER + e) * D_STATE) * NCHUNK + c;
    #pragma unroll
    for (int n = 0; n < 16; ++n) h[n] = h_init[hbase + (size_t)n * NCHUNK];

    const float*  pdt = dtf   + r0 * D_INNER + e;
    const ushort* px  = xin_b + r0 * D_INNER + e;
    const float*  pz  = xz    + r0 * (2*D_INNER) + D_INNER + e;
    ushort*       py  = y     + r0 * D_INNER + e;

    float dtv = pdt[0], xv = b2f(px[0]), zv = pz[0];

    for (int l = 0; l < CLEN; ++l) {
        float dtn = 0.f, xn2 = 0.f, zn = 0.f;
        if (l + 1 < CLEN) {
            dtn = pdt[(size_t)(l+1) * D_INNER];
            xn2 = b2f(px[(size_t)(l+1) * D_INNER]);
            zn  = pz [(size_t)(l+1) * (2*D_INNER)];
        }
        float dtx = dtv * xv;
        const float4* br = reinterpret_cast<const float4*>(&BCs[l][0]);
        float4 B0 = br[0], B1 = br[1], B2 = br[2], B3 = br[3];
        float Bv[16] = {B0.x,B0.y,B0.z,B0.w, B1.x,B1.y,B1.z,B1.w,
                        B2.x,B2.y,B2.z,B2.w, B3.x,B3.y,B3.z,B3.w};
        #pragma unroll
        for (int n = 0; n < 16; ++n) {
            float ex = __expf(dtv * a[n]);
            h[n] = h[n] * ex + dtx * Bv[n];
        }
        float4 C0 = br[4], C1 = br[5], C2 = br[6], C3 = br[7];
        float Cv[16] = {C0.x,C0.y,C0.z,C0.w, C1.x,C1.y,C1.z,C1.w,
                        C2.x,C2.y,C2.z,C2.w, C3.x,C3.y,C3.z,C3.w};
        float yv = 0.f;
        #pragma unroll
        for (int n = 0; n < 16; ++n) yv += h[n] * Cv[n];

        float g = zv / (1.f + __expf(-zv));         // silu(z)
        py[(size_t)l * D_INNER] = f2b((yv + xv * dskip) * g);

        dtv = dtn; xv = xn2; zv = zn;
    }
}

// ---------------------------------------------------------------- launch
extern "C" void kernel_launch(void* const* d_in, const int* in_sizes, int n_in,
                              void* d_out, int out_size, void* d_ws, size_t ws_size,
                              hipStream_t stream)
{
    const int*   tokens       = (const int*)  d_in[0];
    const float* embed        = (const float*)d_in[1];
    const float* norm_w       = (const float*)d_in[2];
    const float* in_proj_w    = (const float*)d_in[3];
    const float* conv_w       = (const float*)d_in[4];
    const float* conv_b       = (const float*)d_in[5];
    const float* x_proj_w     = (const float*)d_in[6];
    const float* dt_proj_w    = (const float*)d_in[7];
    const float* dt_proj_b    = (const float*)d_in[8];
    const float* A_log        = (const float*)d_in[9];
    const float* D_param      = (const float*)d_in[10];
    const float* out_proj_w   = (const float*)d_in[11];
    const float* final_norm_w = (const float*)d_in[12];
    float* out = (float*)d_out;

    // ---- workspace map (float offsets), ~33.6 MB
    float* ws = (float*)d_ws;
    float*  x      = ws;                          // 3,145,728
    float*  proj   = ws + 3145728;                // 458,752
    ushort* xn_b   = (ushort*)(ws + 3604480);     // 3,145,728 us
    ushort* inw_b  = (ushort*)(ws + 5177344);     // 2,359,296 us
    ushort* outw_b = (ushort*)(ws + 6356992);     // 1,179,648 us
    ushort* emb_b  = (ushort*)(ws + 6946816);     // 5120*384 us (rows>=5000: junk, cols discarded)
    ushort* xpw_b  = (ushort*)(ws + 7929856);     // 4*128*768 us
    ushort* dtw_b  = (ushort*)(ws + 8126464);     // 4*768*32 us
    ushort* proj_b = (ushort*)(ws + 8175616);     // 8192*56 us -> ends 8,404,992

    // ---- big scratch in d_out (40,960,000 floats; all dead before lm_head)
    float*  xz     = out;                         //  0 .. 12,582,912
    float*  dtf    = out + 18874368;              // .. 25,165,824
    ushort* y_b    = (ushort*)(out + 25165824);   // .. 28,311,552 (6,291,456 us)
    ushort* xin_b  = (ushort*)(out + 28311552);   // .. 31,457,280 (6,291,456 us)
    float*  h_end  = out + 31457280;              // .. 34,603,008
    float*  decay  = out + 34603008;              // .. 37,748,736
    float*  h_init = out + 37748736;              // .. 40,894,464 (< 40,960,000)

    dim3 blk(256);

    // one-shot weight conversions
    f2b_k<<<(N_LAYER*2*D_INNER*D_MODEL/4 + 255)/256, blk, 0, stream>>>(in_proj_w,  inw_b,  N_LAYER*2*D_INNER*D_MODEL/4);
    f2b_k<<<(N_LAYER*D_MODEL*D_INNER/4  + 255)/256, blk, 0, stream>>>(out_proj_w, outw_b, N_LAYER*D_MODEL*D_INNER/4);
    f2b_k<<<(VOCAB*D_MODEL/4            + 255)/256, blk, 0, stream>>>(embed,      emb_b,  VOCAB*D_MODEL/4);
    pad_xpw<<<N_LAYER*128*768/256, blk, 0, stream>>>(x_proj_w, xpw_b);
    pad_dtw<<<N_LAYER*768*32/256,  blk, 0, stream>>>(dt_proj_w, dtw_b);

    embed_gather<<<ROWS*96/256, blk, 0, stream>>>(tokens, embed, x);

    for (int i = 0; i < N_LAYER; ++i) {
        rmsnorm_k<<<ROWS/4, blk, 0, stream>>>(x, norm_w + i*D_MODEL, xn_b);
        // in_proj: 8192 x 1536 x 384
        gemm_lds<128,128,0><<<dim3(12, 64), blk, 0, stream>>>(
            xn_b, D_MODEL, inw_b + (size_t)i*2*D_INNER*D_MODEL, D_MODEL,
            xz, 2*D_INNER, nullptr, nullptr, 2*D_INNER, D_MODEL);
        // conv + silu -> xin bf16
        conv_silu_k<<<ROWS*D_INNER/256, blk, 0, stream>>>(
            xz, conv_w + i*D_INNER*D_CONV, conv_b + i*D_INNER, xin_b);
        // x_proj: 8192 x 56 x 768 (64-col tile) -> proj f32 + bf16
        gemm_lds<64,64,3><<<dim3(1, 128), blk, 0, stream>>>(
            xin_b, D_INNER, xpw_b + (size_t)i*128*D_INNER, D_INNER,
            proj, 56, proj_b, nullptr, 56, D_INNER);
        // dt_proj + softplus: 8192 x 768 x 32 (K padded)
        gemm_lds<128,128,1><<<dim3(6, 64), blk, 0, stream>>>(
            proj_b, 56, dtw_b + (size_t)i*D_INNER*32, 32,
            dtf, D_INNER, nullptr, dt_proj_b + i*D_INNER, D_INNER, 32);
        // chunked selective scan (register-state layout)
        scan_p1<<<dim3(3, NCHUNK, BATCH), blk, 0, stream>>>(
            dtf, xin_b, proj, A_log + (size_t)i*D_INNER*D_STATE, h_end, decay);
        scan_p2<<<BATCH*D_INNER*D_STATE/4, blk, 0, stream>>>(h_end, decay, h_init);
        scan_p3<<<dim3(3, NCHUNK, BATCH), blk, 0, stream>>>(
            dtf, xin_b, xz, proj, A_log + (size_t)i*D_INNER*D_STATE,
            D_param + i*D_INNER, h_init, y_b);
        // out_proj + residual: 8192 x 384 x 768, x += ...
        gemm_lds<128,64,2><<<dim3(6, 64), blk, 0, stream>>>(
            y_b, D_INNER, outw_b + (size_t)i*D_MODEL*D_INNER, D_INNER,
            x, D_MODEL, nullptr, nullptr, D_MODEL, D_INNER);
    }

    rmsnorm_k<<<ROWS/4, blk, 0, stream>>>(x, final_norm_w, xn_b);
    // lm_head: 8192 x 5000 x 384 (overwrites ALL of d_out)
    gemm_lds<128,128,0><<<dim3(40, 64), blk, 0, stream>>>(
        xn_b, D_MODEL, emb_b, D_MODEL, out, VOCAB, nullptr, nullptr, VOCAB, D_MODEL);
}